// Round 4
// baseline (615.429 us; speedup 1.0000x reference)
//
#include <hip/hip_runtime.h>
#include <math.h>

#define N_TOK 32768
#define DIM 512
#define NE 8
#define NF 2048
#define CCAP 4096

typedef __attribute__((ext_vector_type(4))) float floatx4;
typedef __attribute__((ext_vector_type(8))) short shortx8;
typedef __attribute__((ext_vector_type(4))) short shortx4;

__device__ __forceinline__ short f2bf(float f) {
  union { float f; unsigned u; } v; v.f = f;
  unsigned r = v.u + 0x7FFFu + ((v.u >> 16) & 1u);
  return (short)(r >> 16);
}

__device__ __forceinline__ float bf2f(short s) {
  union { unsigned u; float f; } v; v.u = ((unsigned)(unsigned short)s) << 16;
  return v.f;
}

__device__ __forceinline__ unsigned f2key(float f) {
  union { float f; unsigned u; } v; v.f = f;
  return (v.u & 0x80000000u) ? ~v.u : (v.u | 0x80000000u);
}

__device__ __forceinline__ void gll16(const void* g, void* l) {
  __builtin_amdgcn_global_load_lds(
      (const __attribute__((address_space(1))) void*)g,
      (__attribute__((address_space(3))) void*)l, 16, 0, 0);
}

__device__ __forceinline__ float fast_gelu(float h) {
  float u = 0.7978845608f * (h + 0.044715f * h * h * h);
  float au = fabsf(u) * 2.885390082f;  // 2*log2(e)*|u|
  float z = __builtin_amdgcn_exp2f(au);
  float th = 1.0f - 2.0f * __builtin_amdgcn_rcpf(1.0f + z);
  th = copysignf(th, u);
  return 0.5f * h * (1.0f + th);
}

// stage a 128x64 bf16 A-tile (16KB) via 4 global_load_lds per thread; advances pointers
__device__ __forceinline__ void stage4_adv(const short** ap, short* dst, int t) {
#pragma unroll
  for (int i = 0; i < 4; i++) gll16(ap[i], dst + i * 2048 + t * 8);
#pragma unroll
  for (int i = 0; i < 4; i++) ap[i] += 64;
}

// stage for gemm2 (fixed base + kk offset), rows i*32 + t>>3
__device__ __forceinline__ void stage4_g2(const short* gA, short* dst, int t, int kk) {
#pragma unroll
  for (int i = 0; i < 4; i++)
    gll16(gA + (size_t)i * 32 * NF + kk * 64, dst + i * 2048 + t * 8);
}

// load 8 B-fragments (one 64-K-step, 64 cols) into registers
__device__ __forceinline__ void loadB(const short* gB, int koff, int ldb, shortx8* bf) {
#pragma unroll
  for (int g = 0; g < 2; g++)
#pragma unroll
    for (int j = 0; j < 4; j++)
      bf[g * 4 + j] = *(const shortx8*)(gB + (size_t)j * 16 * ldb + koff + g * 32);
}

// one 64-K-step of MFMA for a 64x64 wave tile: 2 g-groups x 4 i x 4 j
__device__ __forceinline__ void compute64w(const short* ldsA, const shortx8* bf,
                                           floatx4 (*acc)[4], int arow, int lx, int q) {
#pragma unroll
  for (int g = 0; g < 2; g++) {
    const int pu = (((g << 2) | q) ^ lx) << 3;
#pragma unroll
    for (int i = 0; i < 4; i++) {
      shortx8 af = *(const shortx8*)&ldsA[(arow + i * 16) * 64 + pu];
#pragma unroll
      for (int j = 0; j < 4; j++)
        acc[i][j] = __builtin_amdgcn_mfma_f32_16x16x32_bf16(af, bf[g * 4 + j], acc[i][j], 0, 0, 0);
    }
  }
}

// generalized expert->XCD swizzle (bijective; z in {1,2,4,8})
__device__ __forceinline__ void xcd_map(int& bx, int& by, int& zi) {
  int lid = blockIdx.x + gridDim.x * (blockIdx.y + gridDim.y * blockIdx.z);
  int k = 8 / (int)gridDim.z;
  int x = lid & 7, rem = lid >> 3;
  zi = x / k;
  int bxy = rem * k + (x % k);
  bx = bxy % (int)gridDim.x;
  by = bxy / (int)gridDim.x;
}

// ============ prep: W1/W2 transpose+convert, x->bf16, router logits, cnt zero ============
__global__ __launch_bounds__(256) void k_prep(
    const float* __restrict__ x, const float* __restrict__ W1,
    const float* __restrict__ W2, const float* __restrict__ Wr,
    short* __restrict__ xb, short* __restrict__ w1t, short* __restrict__ w2t,
    float* __restrict__ logitsT, int* __restrict__ cnt) {
  __shared__ float tl[64 * 68];
  const int b = blockIdx.x, t = threadIdx.x;
  if (b < 4096) {
    const float* in;
    short* o;
    int R, C, c0, r0;
    if (b < 2048) {
      int e = b >> 8, tlid = b & 255;
      in = W1 + (size_t)e * DIM * NF;
      o = w1t + (size_t)e * NF * DIM;
      R = DIM; C = NF;
      c0 = (tlid & 31) * 64; r0 = (tlid >> 5) * 64;
    } else {
      int bb = b - 2048;
      int e = bb >> 8, tlid = bb & 255;
      in = W2 + (size_t)e * NF * DIM;
      o = w2t + (size_t)e * DIM * NF;
      R = NF; C = DIM;
      c0 = (tlid & 7) * 64; r0 = (tlid >> 3) * 64;
    }
    const int r = t >> 4, cq = (t & 15) * 4;
#pragma unroll
    for (int ii = 0; ii < 4; ii++) {
      floatx4 v = *(const floatx4*)&in[(size_t)(r0 + r + 16 * ii) * C + c0 + cq];
      *(floatx4*)&tl[(r + 16 * ii) * 68 + cq] = v;
    }
    __syncthreads();
    const int cc = t >> 2, rq = (t & 3) * 16;
    shortx8 o0, o1;
#pragma unroll
    for (int k = 0; k < 8; k++) o0[k] = f2bf(tl[(rq + k) * 68 + cc]);
#pragma unroll
    for (int k = 0; k < 8; k++) o1[k] = f2bf(tl[(rq + 8 + k) * 68 + cc]);
    size_t ob = (size_t)(c0 + cc) * R + r0 + rq;
    *(shortx8*)&o[ob] = o0;
    *(shortx8*)&o[ob + 8] = o1;
  } else if (b < 4608) {
    // x -> bf16
    const int base = (b - 4096) * 8192 + t;
#pragma unroll
    for (int i = 0; i < 32; i++) {
      floatx4 v = *(const floatx4*)&x[(size_t)(base + i * 256) * 4];
      shortx4 s;
      s.x = f2bf(v.x); s.y = f2bf(v.y); s.z = f2bf(v.z); s.w = f2bf(v.w);
      *(shortx4*)&xb[(size_t)(base + i * 256) * 4] = s;
    }
  } else if (b < 5632) {
    // router logits (fp64 accumulate), logitsT[e][n]
    const int lane = t & 63;
    const int wave = (b - 4608) * 4 + (t >> 6);
    float wr[64];
#pragma unroll
    for (int i = 0; i < 16; i++)
      *(floatx4*)&wr[i * 4] = *(const floatx4*)&Wr[lane * 64 + i * 4];
    for (int n = wave; n < N_TOK; n += 4096) {
      const float* xr = x + (size_t)n * DIM + lane * 8;
      floatx4 x0 = *(const floatx4*)xr;
      floatx4 x1 = *(const floatx4*)(xr + 4);
      float xs[8] = {x0.x, x0.y, x0.z, x0.w, x1.x, x1.y, x1.z, x1.w};
      double acc[8];
#pragma unroll
      for (int e2 = 0; e2 < 8; e2++) acc[e2] = 0.0;
#pragma unroll
      for (int j = 0; j < 8; j++) {
        double xv = (double)xs[j];
#pragma unroll
        for (int e2 = 0; e2 < 8; e2++) acc[e2] += xv * (double)wr[j * 8 + e2];
      }
#pragma unroll
      for (int e2 = 0; e2 < 8; e2++) {
#pragma unroll
        for (int off2 = 32; off2 > 0; off2 >>= 1)
          acc[e2] += __shfl_xor(acc[e2], off2);
      }
      double rv = acc[0];
#pragma unroll
      for (int e2 = 1; e2 < 8; e2++)
        if (lane == e2) rv = acc[e2];
      if (lane < 8) logitsT[(size_t)lane * N_TOK + n] = (float)rv;
    }
  } else {
    // zero inverse-index counters
#pragma unroll
    for (int i = 0; i < 128; i++) cnt[t + 256 * i] = 0;
  }
}

// ============ exact top-C via register bisection + ballot compaction (+ inverse index) ============
__global__ __launch_bounds__(1024) void k_select(const float* __restrict__ logitsT,
                                                 int* __restrict__ sel_idx,
                                                 float* __restrict__ sel_val,
                                                 int* __restrict__ cnt,
                                                 int* __restrict__ slots) {
  __shared__ float redf[16];
  __shared__ unsigned redu[16];
  __shared__ float s_max, s_inv;
  __shared__ unsigned s_tot;
  __shared__ unsigned s_cnt[2];
  const int e = blockIdx.x, t = threadIdx.x;
  const int wid = t >> 6, lane = t & 63;
  const float* lg = logitsT + (size_t)e * N_TOK;
  float lv[32];
  unsigned kv[32];
#pragma unroll
  for (int i = 0; i < 32; i++) lv[i] = lg[i * 1024 + t];
#pragma unroll
  for (int i = 0; i < 32; i++) kv[i] = f2key(lv[i]);
  float m = lv[0];
#pragma unroll
  for (int i = 1; i < 32; i++) m = fmaxf(m, lv[i]);
#pragma unroll
  for (int o = 32; o > 0; o >>= 1) m = fmaxf(m, __shfl_xor(m, o));
  if (lane == 0) redf[wid] = m;
  __syncthreads();
  if (t == 0) {
    float v = redf[0];
    for (int i = 1; i < 16; i++) v = fmaxf(v, redf[i]);
    s_max = v;
  }
  __syncthreads();
  m = s_max;
  float s = 0.f;
#pragma unroll
  for (int i = 0; i < 32; i++) s += expf(lv[i] - m);
#pragma unroll
  for (int o = 32; o > 0; o >>= 1) s += __shfl_xor(s, o);
  if (lane == 0) redf[wid] = s;
  __syncthreads();
  if (t == 0) {
    float v = 0.f;
    for (int i = 0; i < 16; i++) v += redf[i];
    s_inv = 1.0f / v;
  }
  unsigned T = 0;
  for (int bb = 31; bb >= 0; --bb) {
    unsigned cand = T | (1u << bb);
    unsigned c = 0;
#pragma unroll
    for (int i = 0; i < 32; i++) c += (kv[i] >= cand) ? 1u : 0u;
#pragma unroll
    for (int o = 32; o > 0; o >>= 1) c += __shfl_xor(c, o);
    if (lane == 0) redu[wid] = c;
    __syncthreads();
    if (t == 0) {
      unsigned v = 0;
      for (int i = 0; i < 16; i++) v += redu[i];
      s_tot = v;
    }
    __syncthreads();
    if (s_tot >= CCAP) T = cand;
  }
  {
    unsigned c = 0;
#pragma unroll
    for (int i = 0; i < 32; i++) c += (kv[i] > T) ? 1u : 0u;
#pragma unroll
    for (int o = 32; o > 0; o >>= 1) c += __shfl_xor(c, o);
    if (lane == 0) redu[wid] = c;
    __syncthreads();
    if (t == 0) {
      unsigned v = 0;
      for (int i = 0; i < 16; i++) v += redu[i];
      s_tot = v;
      s_cnt[0] = 0;
      s_cnt[1] = 0;
    }
    __syncthreads();
  }
  const unsigned rr = CCAP - s_tot;
  const float inv = s_inv;
  const unsigned long long lmask = (1ull << lane) - 1ull;
#pragma unroll
  for (int i = 0; i < 32; i++) {
    int n = i * 1024 + t;
    bool gt = kv[i] > T;
    bool eq = kv[i] == T;
    unsigned long long mg = __ballot(gt);
    unsigned long long mq = __ballot(eq);
    unsigned bg = 0, bq = 0;
    if (lane == 0) {
      if (mg) bg = atomicAdd(&s_cnt[0], (unsigned)__popcll(mg));
      if (mq) bq = atomicAdd(&s_cnt[1], (unsigned)__popcll(mq));
    }
    bg = __shfl(bg, 0);
    bq = __shfl(bq, 0);
    int pos = -1;
    if (gt) {
      pos = (int)(bg + (unsigned)__popcll(mg & lmask));
    } else if (eq) {
      unsigned qq = bq + (unsigned)__popcll(mq & lmask);
      if (qq < rr) pos = (int)(CCAP - rr + qq);
    }
    if (pos >= 0) {
      sel_idx[e * CCAP + pos] = n;
      sel_val[e * CCAP + pos] = expf(lv[i] - m) * inv;
      int s2 = atomicAdd(&cnt[n], 1);
      slots[n * 8 + s2] = (e << 16) | pos;
    }
  }
}

// ============ GEMM1: H = gelu(gather(xb)[128-tile,512] @ W1 + b1) ============
// block 128x128, 4 waves of 64x64 (acc=64 AGPR), BK=64 dbuf in 32KB LDS.
// Targets 16 waves/CU (4 blocks). B loads issued before gll16 prefetch (vmcnt order).
__global__ __launch_bounds__(256, 4) void k_gemm1(
    const short* __restrict__ xb, const short* __restrict__ w1t,
    const float* __restrict__ b1, const int* __restrict__ sel_idx,
    short* __restrict__ H, int e0) {
  __shared__ char smem[32768];  // dbuf 2x16KB; epilogue chunk (64x136x2=17408) unioned
  short* ldsA0 = (short*)smem;
  short* ldsA1 = (short*)(smem + 16384);

  int bx, by, zi;
  xcd_map(bx, by, zi);
  const int e = e0 + zi;
  const int c0 = by * 128;
  const int f0 = bx * 128;
  const int t = threadIdx.x;
  const int lane = t & 63;
  const int w = t >> 6;
  const int wm = w & 1, wn = w >> 1;
  const int row8 = t >> 3;               // 0..31
  const int su = (t & 7) ^ (row8 & 7);   // XOR slot swizzle (row&7 == row8&7 since rows step by 32)

  const short* gAp[4];
#pragma unroll
  for (int i = 0; i < 4; i++) {
    int tok = sel_idx[e * CCAP + c0 + i * 32 + row8];
    gAp[i] = xb + (size_t)tok * DIM + su * 8;
  }
  const short* gB = w1t + ((size_t)(e * NF + f0 + wn * 64 + (lane & 15))) * DIM + (lane >> 4) * 8;

  floatx4 acc[4][4];
#pragma unroll
  for (int i = 0; i < 4; i++)
#pragma unroll
    for (int j = 0; j < 4; j++) acc[i][j] = (floatx4){0.f, 0.f, 0.f, 0.f};

  const int arow = wm * 64 + (lane & 15);
  const int lx = lane & 7, q = lane >> 4;

  stage4_adv(gAp, ldsA0, t);
  __syncthreads();

  for (int kk = 0; kk < DIM / 64; kk += 2) {
    {
      shortx8 bf[8];
      loadB(gB, kk * 64, DIM, bf);            // older: B for tile kk
      __builtin_amdgcn_sched_barrier(0);
      stage4_adv(gAp, ldsA1, t);              // younger: prefetch kk+1
      __builtin_amdgcn_sched_barrier(0);
      compute64w(ldsA0, bf, acc, arow, lx, q);
      __syncthreads();
    }
    {
      shortx8 bf[8];
      loadB(gB, (kk + 1) * 64, DIM, bf);
      __builtin_amdgcn_sched_barrier(0);
      if (kk + 2 < DIM / 64) stage4_adv(gAp, ldsA0, t);
      __builtin_amdgcn_sched_barrier(0);
      compute64w(ldsA1, bf, acc, arow, lx, q);
      __syncthreads();
    }
  }

  // epilogue: two 64-row chunks (chunk == wm): gelu -> LDS restage -> coalesced stores
  short* ep = (short*)smem;
  const int colL = wn * 64 + (lane & 15);
  const int rowL = (lane >> 4) << 2;  // 0,4,8,12 within each 16-row band
  short* Hp = H + (size_t)zi * CCAP * NF;
#pragma unroll
  for (int ch = 0; ch < 2; ch++) {
    if (wm == ch) {
#pragma unroll
      for (int j = 0; j < 4; j++) {
        float bv = b1[e * NF + f0 + colL + j * 16];
#pragma unroll
        for (int i = 0; i < 4; i++) {
#pragma unroll
          for (int r = 0; r < 4; r++) {
            float h = acc[i][j][r] + bv;
            ep[(i * 16 + rowL + r) * 136 + colL + j * 16] = f2bf(fast_gelu(h));
          }
        }
      }
    }
    __syncthreads();
    const int chunk = t & 15;
#pragma unroll
    for (int it = 0; it < 4; it++) {
      int r = (t >> 4) + 16 * it;
      shortx8 v = *(const shortx8*)&ep[r * 136 + chunk * 8];
      *(shortx8*)&Hp[(size_t)(c0 + ch * 64 + r) * NF + f0 + chunk * 8] = v;
    }
    __syncthreads();
  }
}

// ============ GEMM2: oute[e] = H @ W2 + b2 (unscaled, bf16, NO atomics) ============
__global__ __launch_bounds__(256, 4) void k_gemm2(
    const short* __restrict__ H, const short* __restrict__ w2t,
    const float* __restrict__ b2, short* __restrict__ oute, int e0) {
  __shared__ char smem[32768];
  short* ldsA0 = (short*)smem;
  short* ldsA1 = (short*)(smem + 16384);

  int bx, by, zi;
  xcd_map(bx, by, zi);
  const int e = e0 + zi;
  const int c0 = by * 128;
  const int d0 = bx * 128;
  const int t = threadIdx.x;
  const int lane = t & 63;
  const int w = t >> 6;
  const int wm = w & 1, wn = w >> 1;
  const int row8 = t >> 3;
  const int su = (t & 7) ^ (row8 & 7);

  const short* gA = H + ((size_t)zi * CCAP + c0 + row8) * NF + su * 8;
  const short* gB = w2t + ((size_t)(e * DIM + d0 + wn * 64 + (lane & 15))) * NF + (lane >> 4) * 8;

  floatx4 acc[4][4];
#pragma unroll
  for (int i = 0; i < 4; i++)
#pragma unroll
    for (int j = 0; j < 4; j++) acc[i][j] = (floatx4){0.f, 0.f, 0.f, 0.f};

  const int arow = wm * 64 + (lane & 15);
  const int lx = lane & 7, q = lane >> 4;

  stage4_g2(gA, ldsA0, t, 0);
  __syncthreads();

  for (int kk = 0; kk < NF / 64; kk += 2) {
    {
      shortx8 bf[8];
      loadB(gB, kk * 64, NF, bf);
      __builtin_amdgcn_sched_barrier(0);
      stage4_g2(gA, ldsA1, t, kk + 1);
      __builtin_amdgcn_sched_barrier(0);
      compute64w(ldsA0, bf, acc, arow, lx, q);
      __syncthreads();
    }
    {
      shortx8 bf[8];
      loadB(gB, (kk + 1) * 64, NF, bf);
      __builtin_amdgcn_sched_barrier(0);
      if (kk + 2 < NF / 64) stage4_g2(gA, ldsA0, t, kk + 2);
      __builtin_amdgcn_sched_barrier(0);
      compute64w(ldsA1, bf, acc, arow, lx, q);
      __syncthreads();
    }
  }

  // epilogue: two 64-row chunks: bias -> bf16 -> LDS restage -> coalesced stores
  short* ep = (short*)smem;
  const int colL = wn * 64 + (lane & 15);
  const int rowL = (lane >> 4) << 2;
#pragma unroll
  for (int ch = 0; ch < 2; ch++) {
    if (wm == ch) {
#pragma unroll
      for (int j = 0; j < 4; j++) {
        float bv = b2[e * DIM + d0 + colL + j * 16];
#pragma unroll
        for (int i = 0; i < 4; i++) {
#pragma unroll
          for (int r = 0; r < 4; r++) {
            float o = acc[i][j][r] + bv;
            ep[(i * 16 + rowL + r) * 136 + colL + j * 16] = f2bf(o);
          }
        }
      }
    }
    __syncthreads();
    const int chunk = t & 15;
#pragma unroll
    for (int it = 0; it < 4; it++) {
      int r = (t >> 4) + 16 * it;
      shortx8 v = *(const shortx8*)&ep[r * 136 + chunk * 8];
      *(shortx8*)&oute[((size_t)e * CCAP + c0 + ch * 64 + r) * DIM + d0 + chunk * 8] = v;
    }
    __syncthreads();
  }
}

// ============ combine: out[token] = sum over selected (e,pos) of val * oute row ============
// also writes zeros for unselected tokens (out is no longer pre-zeroed)
__global__ __launch_bounds__(256) void k_combine(
    const short* __restrict__ oute, const int* __restrict__ cnt,
    const int* __restrict__ slots, const float* __restrict__ sel_val,
    float* __restrict__ out) {
  const int lane = threadIdx.x & 63;
  const int wid = threadIdx.x >> 6;
  const int n = blockIdx.x * 4 + wid;
  const int c = cnt[n];
  float acc[8];
#pragma unroll
  for (int k = 0; k < 8; k++) acc[k] = 0.f;
  for (int s = 0; s < c; ++s) {
    int sl = slots[n * 8 + s];
    int e = sl >> 16, pos = sl & 0xFFFF;
    float val = sel_val[e * CCAP + pos];
    shortx8 v = *(const shortx8*)&oute[((size_t)e * CCAP + pos) * DIM + lane * 8];
#pragma unroll
    for (int k = 0; k < 8; k++) acc[k] += val * bf2f(v[k]);
  }
  floatx4 o0 = {acc[0], acc[1], acc[2], acc[3]};
  floatx4 o1 = {acc[4], acc[5], acc[6], acc[7]};
  *(floatx4*)&out[(size_t)n * DIM + lane * 8] = o0;
  *(floatx4*)&out[(size_t)n * DIM + lane * 8 + 4] = o1;
}

extern "C" void kernel_launch(void* const* d_in, const int* in_sizes, int n_in,
                              void* d_out, int out_size, void* d_ws, size_t ws_size,
                              hipStream_t stream) {
  const float* x = (const float*)d_in[0];
  const float* Wr = (const float*)d_in[1];
  const float* W1 = (const float*)d_in[2];
  const float* b1 = (const float*)d_in[3];
  const float* W2 = (const float*)d_in[4];
  const float* b2 = (const float*)d_in[5];
  float* out = (float*)d_out;

  char* p = (char*)d_ws;
  size_t off = 0;
  auto carve = [&](size_t bytes) {
    void* r = p + off;
    off = (off + bytes + 255) & ~(size_t)255;
    return r;
  };
  short* xb = (short*)carve((size_t)N_TOK * DIM * 2);
  short* w1t = (short*)carve((size_t)NE * NF * DIM * 2);
  short* w2t = (short*)carve((size_t)NE * DIM * NF * 2);
  float* logitsT = (float*)carve((size_t)NE * N_TOK * 4);
  int* selidx = (int*)carve((size_t)NE * CCAP * 4);
  float* selval = (float*)carve((size_t)NE * CCAP * 4);
  int* cnt = (int*)carve((size_t)N_TOK * 4);
  int* slots = (int*)carve((size_t)N_TOK * 8 * 4);
  short* oute = (short*)carve((size_t)NE * CCAP * DIM * 2);
  const size_t hbytes = (size_t)CCAP * NF * 2;
  int g = 1;
  if (off + 8 * hbytes <= ws_size) g = 8;
  else if (off + 4 * hbytes <= ws_size) g = 4;
  else if (off + 2 * hbytes <= ws_size) g = 2;
  short* Hbuf = (short*)carve((size_t)g * hbytes);

  k_prep<<<5633, 256, 0, stream>>>(x, W1, W2, Wr, xb, w1t, w2t, logitsT, cnt);
  k_select<<<NE, 1024, 0, stream>>>(logitsT, selidx, selval, cnt, slots);
  for (int e0 = 0; e0 < NE; e0 += g) {
    k_gemm1<<<dim3(NF / 128, CCAP / 128, g), 256, 0, stream>>>(xb, w1t, b1, selidx, Hbuf, e0);
    k_gemm2<<<dim3(DIM / 128, CCAP / 128, g), 256, 0, stream>>>(Hbuf, w2t, b2, oute, e0);
  }
  k_combine<<<N_TOK / 4, 256, 0, stream>>>(oute, cnt, slots, selval, out);
}

// Round 6
// 596.736 us; speedup vs baseline: 1.0313x; 1.0313x over previous
//
#include <hip/hip_runtime.h>
#include <math.h>

#define N_TOK 32768
#define DIM 512
#define NE 8
#define NF 2048
#define CCAP 4096

typedef __attribute__((ext_vector_type(4))) float floatx4;
typedef __attribute__((ext_vector_type(8))) short shortx8;
typedef __attribute__((ext_vector_type(4))) short shortx4;

__device__ __forceinline__ short f2bf(float f) {
  union { float f; unsigned u; } v; v.f = f;
  unsigned r = v.u + 0x7FFFu + ((v.u >> 16) & 1u);
  return (short)(r >> 16);
}

__device__ __forceinline__ float bf2f(short s) {
  union { unsigned u; float f; } v; v.u = ((unsigned)(unsigned short)s) << 16;
  return v.f;
}

__device__ __forceinline__ unsigned f2key(float f) {
  union { float f; unsigned u; } v; v.f = f;
  return (v.u & 0x80000000u) ? ~v.u : (v.u | 0x80000000u);
}

__device__ __forceinline__ void gll16(const void* g, void* l) {
  __builtin_amdgcn_global_load_lds(
      (const __attribute__((address_space(1))) void*)g,
      (__attribute__((address_space(3))) void*)l, 16, 0, 0);
}

__device__ __forceinline__ float fast_gelu(float h) {
  float u = 0.7978845608f * (h + 0.044715f * h * h * h);
  float au = fabsf(u) * 2.885390082f;  // 2*log2(e)*|u|
  float z = __builtin_amdgcn_exp2f(au);
  float th = 1.0f - 2.0f * __builtin_amdgcn_rcpf(1.0f + z);
  th = copysignf(th, u);
  return 0.5f * h * (1.0f + th);
}

// stage a 128x64 bf16 A-tile (16KB): gemm1 variant, 4 gathered row-group bases + kk offset
__device__ __forceinline__ void stage4_g1(const short* const* ab, short* dst, int t, int kk) {
#pragma unroll
  for (int i = 0; i < 4; i++) gll16(ab[i] + kk * 64, dst + i * 2048 + t * 8);
}

// gemm2 variant: contiguous rows, fixed base + kk offset
__device__ __forceinline__ void stage4_g2(const short* gA, short* dst, int t, int kk) {
#pragma unroll
  for (int i = 0; i < 4; i++)
    gll16(gA + (size_t)i * 32 * NF + kk * 64, dst + i * 2048 + t * 8);
}

// load 8 B-fragments (one 64-K-step, 64 cols) into registers
__device__ __forceinline__ void loadB(const short* gB, int koff, int ldb, shortx8* bf) {
#pragma unroll
  for (int g = 0; g < 2; g++)
#pragma unroll
    for (int j = 0; j < 4; j++)
      bf[g * 4 + j] = *(const shortx8*)(gB + (size_t)j * 16 * ldb + koff + g * 32);
}

// one 64-K-step of MFMA for a 64x64 wave tile: 2 g-groups x 4 i x 4 j
__device__ __forceinline__ void compute64w(const short* ldsA, const shortx8* bf,
                                           floatx4 (*acc)[4], int arow, int lx, int q) {
#pragma unroll
  for (int g = 0; g < 2; g++) {
    const int pu = (((g << 2) | q) ^ lx) << 3;
#pragma unroll
    for (int i = 0; i < 4; i++) {
      shortx8 af = *(const shortx8*)&ldsA[(arow + i * 16) * 64 + pu];
#pragma unroll
      for (int j = 0; j < 4; j++)
        acc[i][j] = __builtin_amdgcn_mfma_f32_16x16x32_bf16(af, bf[g * 4 + j], acc[i][j], 0, 0, 0);
    }
  }
}

// counted pre-barrier: force stage(kk+1)+B(kk) complete, keep stage(kk+2) (4 gll16) in flight
__device__ __forceinline__ void bar_keep4() {
  __builtin_amdgcn_sched_barrier(0);
  asm volatile("s_waitcnt vmcnt(4)" ::: "memory");
  __builtin_amdgcn_sched_barrier(0);
  __builtin_amdgcn_s_barrier();
  __builtin_amdgcn_sched_barrier(0);
}

// generalized expert->XCD swizzle (bijective; z in {1,2,4,8})
__device__ __forceinline__ void xcd_map(int& bx, int& by, int& zi) {
  int lid = blockIdx.x + gridDim.x * (blockIdx.y + gridDim.y * blockIdx.z);
  int k = 8 / (int)gridDim.z;
  int x = lid & 7, rem = lid >> 3;
  zi = x / k;
  int bxy = rem * k + (x % k);
  bx = bxy % (int)gridDim.x;
  by = bxy / (int)gridDim.x;
}

// ============ prep: W1/W2 transpose+convert, x->bf16, router logits, cnt zero ============
__global__ __launch_bounds__(256) void k_prep(
    const float* __restrict__ x, const float* __restrict__ W1,
    const float* __restrict__ W2, const float* __restrict__ Wr,
    short* __restrict__ xb, short* __restrict__ w1t, short* __restrict__ w2t,
    float* __restrict__ logitsT, int* __restrict__ cnt) {
  __shared__ float tl[64 * 68];
  const int b = blockIdx.x, t = threadIdx.x;
  if (b < 4096) {
    const float* in;
    short* o;
    int R, C, c0, r0;
    if (b < 2048) {
      int e = b >> 8, tlid = b & 255;
      in = W1 + (size_t)e * DIM * NF;
      o = w1t + (size_t)e * NF * DIM;
      R = DIM; C = NF;
      c0 = (tlid & 31) * 64; r0 = (tlid >> 5) * 64;
    } else {
      int bb = b - 2048;
      int e = bb >> 8, tlid = bb & 255;
      in = W2 + (size_t)e * NF * DIM;
      o = w2t + (size_t)e * DIM * NF;
      R = NF; C = DIM;
      c0 = (tlid & 7) * 64; r0 = (tlid >> 3) * 64;
    }
    const int r = t >> 4, cq = (t & 15) * 4;
#pragma unroll
    for (int ii = 0; ii < 4; ii++) {
      floatx4 v = *(const floatx4*)&in[(size_t)(r0 + r + 16 * ii) * C + c0 + cq];
      *(floatx4*)&tl[(r + 16 * ii) * 68 + cq] = v;
    }
    __syncthreads();
    const int cc = t >> 2, rq = (t & 3) * 16;
    shortx8 o0, o1;
#pragma unroll
    for (int k = 0; k < 8; k++) o0[k] = f2bf(tl[(rq + k) * 68 + cc]);
#pragma unroll
    for (int k = 0; k < 8; k++) o1[k] = f2bf(tl[(rq + 8 + k) * 68 + cc]);
    size_t ob = (size_t)(c0 + cc) * R + r0 + rq;
    *(shortx8*)&o[ob] = o0;
    *(shortx8*)&o[ob + 8] = o1;
  } else if (b < 4608) {
    // x -> bf16
    const int base = (b - 4096) * 8192 + t;
#pragma unroll
    for (int i = 0; i < 32; i++) {
      floatx4 v = *(const floatx4*)&x[(size_t)(base + i * 256) * 4];
      shortx4 s;
      s.x = f2bf(v.x); s.y = f2bf(v.y); s.z = f2bf(v.z); s.w = f2bf(v.w);
      *(shortx4*)&xb[(size_t)(base + i * 256) * 4] = s;
    }
  } else if (b < 5632) {
    // router logits (fp64 accumulate), logitsT[e][n]
    const int lane = t & 63;
    const int wave = (b - 4608) * 4 + (t >> 6);
    float wr[64];
#pragma unroll
    for (int i = 0; i < 16; i++)
      *(floatx4*)&wr[i * 4] = *(const floatx4*)&Wr[lane * 64 + i * 4];
    for (int n = wave; n < N_TOK; n += 4096) {
      const float* xr = x + (size_t)n * DIM + lane * 8;
      floatx4 x0 = *(const floatx4*)xr;
      floatx4 x1 = *(const floatx4*)(xr + 4);
      float xs[8] = {x0.x, x0.y, x0.z, x0.w, x1.x, x1.y, x1.z, x1.w};
      double acc[8];
#pragma unroll
      for (int e2 = 0; e2 < 8; e2++) acc[e2] = 0.0;
#pragma unroll
      for (int j = 0; j < 8; j++) {
        double xv = (double)xs[j];
#pragma unroll
        for (int e2 = 0; e2 < 8; e2++) acc[e2] += xv * (double)wr[j * 8 + e2];
      }
#pragma unroll
      for (int e2 = 0; e2 < 8; e2++) {
#pragma unroll
        for (int off2 = 32; off2 > 0; off2 >>= 1)
          acc[e2] += __shfl_xor(acc[e2], off2);
      }
      double rv = acc[0];
#pragma unroll
      for (int e2 = 1; e2 < 8; e2++)
        if (lane == e2) rv = acc[e2];
      if (lane < 8) logitsT[(size_t)lane * N_TOK + n] = (float)rv;
    }
  } else {
    // zero inverse-index counters
#pragma unroll
    for (int i = 0; i < 128; i++) cnt[t + 256 * i] = 0;
  }
}

// ============ exact top-C via register bisection + ballot compaction (+ inverse index) ============
__global__ __launch_bounds__(1024) void k_select(const float* __restrict__ logitsT,
                                                 int* __restrict__ sel_idx,
                                                 float* __restrict__ sel_val,
                                                 int* __restrict__ cnt,
                                                 int* __restrict__ slots) {
  __shared__ float redf[16];
  __shared__ unsigned redu[16];
  __shared__ float s_max, s_inv;
  __shared__ unsigned s_tot;
  __shared__ unsigned s_cnt[2];
  const int e = blockIdx.x, t = threadIdx.x;
  const int wid = t >> 6, lane = t & 63;
  const float* lg = logitsT + (size_t)e * N_TOK;
  float lv[32];
  unsigned kv[32];
#pragma unroll
  for (int i = 0; i < 32; i++) lv[i] = lg[i * 1024 + t];
#pragma unroll
  for (int i = 0; i < 32; i++) kv[i] = f2key(lv[i]);
  float m = lv[0];
#pragma unroll
  for (int i = 1; i < 32; i++) m = fmaxf(m, lv[i]);
#pragma unroll
  for (int o = 32; o > 0; o >>= 1) m = fmaxf(m, __shfl_xor(m, o));
  if (lane == 0) redf[wid] = m;
  __syncthreads();
  if (t == 0) {
    float v = redf[0];
    for (int i = 1; i < 16; i++) v = fmaxf(v, redf[i]);
    s_max = v;
  }
  __syncthreads();
  m = s_max;
  float s = 0.f;
#pragma unroll
  for (int i = 0; i < 32; i++) s += expf(lv[i] - m);
#pragma unroll
  for (int o = 32; o > 0; o >>= 1) s += __shfl_xor(s, o);
  if (lane == 0) redf[wid] = s;
  __syncthreads();
  if (t == 0) {
    float v = 0.f;
    for (int i = 0; i < 16; i++) v += redf[i];
    s_inv = 1.0f / v;
  }
  unsigned T = 0;
  for (int bb = 31; bb >= 0; --bb) {
    unsigned cand = T | (1u << bb);
    unsigned c = 0;
#pragma unroll
    for (int i = 0; i < 32; i++) c += (kv[i] >= cand) ? 1u : 0u;
#pragma unroll
    for (int o = 32; o > 0; o >>= 1) c += __shfl_xor(c, o);
    if (lane == 0) redu[wid] = c;
    __syncthreads();
    if (t == 0) {
      unsigned v = 0;
      for (int i = 0; i < 16; i++) v += redu[i];
      s_tot = v;
    }
    __syncthreads();
    if (s_tot >= CCAP) T = cand;
  }
  {
    unsigned c = 0;
#pragma unroll
    for (int i = 0; i < 32; i++) c += (kv[i] > T) ? 1u : 0u;
#pragma unroll
    for (int o = 32; o > 0; o >>= 1) c += __shfl_xor(c, o);
    if (lane == 0) redu[wid] = c;
    __syncthreads();
    if (t == 0) {
      unsigned v = 0;
      for (int i = 0; i < 16; i++) v += redu[i];
      s_tot = v;
      s_cnt[0] = 0;
      s_cnt[1] = 0;
    }
    __syncthreads();
  }
  const unsigned rr = CCAP - s_tot;
  const float inv = s_inv;
  const unsigned long long lmask = (1ull << lane) - 1ull;
#pragma unroll
  for (int i = 0; i < 32; i++) {
    int n = i * 1024 + t;
    bool gt = kv[i] > T;
    bool eq = kv[i] == T;
    unsigned long long mg = __ballot(gt);
    unsigned long long mq = __ballot(eq);
    unsigned bg = 0, bq = 0;
    if (lane == 0) {
      if (mg) bg = atomicAdd(&s_cnt[0], (unsigned)__popcll(mg));
      if (mq) bq = atomicAdd(&s_cnt[1], (unsigned)__popcll(mq));
    }
    bg = __shfl(bg, 0);
    bq = __shfl(bq, 0);
    int pos = -1;
    if (gt) {
      pos = (int)(bg + (unsigned)__popcll(mg & lmask));
    } else if (eq) {
      unsigned qq = bq + (unsigned)__popcll(mq & lmask);
      if (qq < rr) pos = (int)(CCAP - rr + qq);
    }
    if (pos >= 0) {
      sel_idx[e * CCAP + pos] = n;
      sel_val[e * CCAP + pos] = expf(lv[i] - m) * inv;
      int s2 = atomicAdd(&cnt[n], 1);
      slots[n * 8 + s2] = (e << 16) | pos;
    }
  }
}

// ============ GEMM1: H = gelu(gather(xb)[128-tile,512] @ W1 + b1) ============
// block 128x128, 4 waves of 64x64, BK=64. 3-buffer LDS pipeline, 2-deep prefetch,
// counted vmcnt(4) + raw s_barrier: stage(kk+2) stays in flight across the barrier.
// B loads issued FIRST each iter so B consumption never drains the stage queue.
__global__ __launch_bounds__(256, 3) void k_gemm1(
    const short* __restrict__ xb, const short* __restrict__ w1t,
    const float* __restrict__ b1, const int* __restrict__ sel_idx,
    short* __restrict__ H, int e0) {
  __shared__ char smem[49152];  // 3 x 16KB; epilogue chunk (64x136x2=17408) aliased
  short* l0 = (short*)smem;
  short* l1 = (short*)(smem + 16384);
  short* l2 = (short*)(smem + 32768);

  int bx, by, zi;
  xcd_map(bx, by, zi);
  const int e = e0 + zi;
  const int c0 = by * 128;
  const int f0 = bx * 128;
  const int t = threadIdx.x;
  const int lane = t & 63;
  const int w = t >> 6;
  const int wm = w & 1, wn = w >> 1;
  const int row8 = t >> 3;               // 0..31
  const int su = (t & 7) ^ (row8 & 7);   // XOR slot swizzle on SOURCE (gll16 dest linear)

  const short* gAb[4];
#pragma unroll
  for (int i = 0; i < 4; i++) {
    int tok = sel_idx[e * CCAP + c0 + i * 32 + row8];
    gAb[i] = xb + (size_t)tok * DIM + su * 8;
  }
  const short* gB = w1t + ((size_t)(e * NF + f0 + wn * 64 + (lane & 15))) * DIM + (lane >> 4) * 8;

  floatx4 acc[4][4];
#pragma unroll
  for (int i = 0; i < 4; i++)
#pragma unroll
    for (int j = 0; j < 4; j++) acc[i][j] = (floatx4){0.f, 0.f, 0.f, 0.f};

  const int arow = wm * 64 + (lane & 15);
  const int lx = lane & 7, q = lane >> 4;

  // prologue: stage tiles 0,1; wait for tile 0 only (tile 1 stays in flight)
  stage4_g1(gAb, l0, t, 0);
  stage4_g1(gAb, l1, t, 1);
  bar_keep4();

  short *bA = l0, *bB = l1, *bC = l2;
  const int NK = DIM / 64;
  for (int kk = 0; kk < NK; ++kk) {
    shortx8 bf[8];
    loadB(gB, kk * 64, DIM, bf);              // oldest this iter: B(kk)
    __builtin_amdgcn_sched_barrier(0);
    if (kk + 2 < NK) stage4_g1(gAb, bC, t, kk + 2);  // younger: stage(kk+2)
    __builtin_amdgcn_sched_barrier(0);
    compute64w(bA, bf, acc, arow, lx, q);     // B waits keep stage(kk+2) in flight
    bar_keep4();                              // forces stage(kk+1)+B(kk); keeps stage(kk+2)
    short* tmp = bA; bA = bB; bB = bC; bC = tmp;
  }

  // epilogue: two 64-row chunks (chunk == wm): gelu -> LDS restage -> coalesced stores
  short* ep = (short*)smem;
  const int colL = wn * 64 + (lane & 15);
  const int rowL = (lane >> 4) << 2;  // 0,4,8,12 within each 16-row band
  short* Hp = H + (size_t)zi * CCAP * NF;
#pragma unroll
  for (int ch = 0; ch < 2; ch++) {
    if (wm == ch) {
#pragma unroll
      for (int j = 0; j < 4; j++) {
        float bv = b1[e * NF + f0 + colL + j * 16];
#pragma unroll
        for (int i = 0; i < 4; i++) {
#pragma unroll
          for (int r = 0; r < 4; r++) {
            float h = acc[i][j][r] + bv;
            ep[(i * 16 + rowL + r) * 136 + colL + j * 16] = f2bf(fast_gelu(h));
          }
        }
      }
    }
    __syncthreads();
    const int chunk = t & 15;
#pragma unroll
    for (int it = 0; it < 4; it++) {
      int r = (t >> 4) + 16 * it;
      shortx8 v = *(const shortx8*)&ep[r * 136 + chunk * 8];
      *(shortx8*)&Hp[(size_t)(c0 + ch * 64 + r) * NF + f0 + chunk * 8] = v;
    }
    __syncthreads();
  }
}

// ============ GEMM2: oute[e] = H @ W2 + b2 (unscaled, bf16, NO atomics) ============
// Same 3-buffer counted-vmcnt pipeline; K=2048 -> 32 steps.
__global__ __launch_bounds__(256, 3) void k_gemm2(
    const short* __restrict__ H, const short* __restrict__ w2t,
    const float* __restrict__ b2, short* __restrict__ oute, int e0) {
  __shared__ char smem[49152];
  short* l0 = (short*)smem;
  short* l1 = (short*)(smem + 16384);
  short* l2 = (short*)(smem + 32768);

  int bx, by, zi;
  xcd_map(bx, by, zi);
  const int e = e0 + zi;
  const int c0 = by * 128;
  const int d0 = bx * 128;
  const int t = threadIdx.x;
  const int lane = t & 63;
  const int w = t >> 6;
  const int wm = w & 1, wn = w >> 1;
  const int row8 = t >> 3;
  const int su = (t & 7) ^ (row8 & 7);

  const short* gA = H + ((size_t)zi * CCAP + c0 + row8) * NF + su * 8;
  const short* gB = w2t + ((size_t)(e * DIM + d0 + wn * 64 + (lane & 15))) * NF + (lane >> 4) * 8;

  floatx4 acc[4][4];
#pragma unroll
  for (int i = 0; i < 4; i++)
#pragma unroll
    for (int j = 0; j < 4; j++) acc[i][j] = (floatx4){0.f, 0.f, 0.f, 0.f};

  const int arow = wm * 64 + (lane & 15);
  const int lx = lane & 7, q = lane >> 4;

  stage4_g2(gA, l0, t, 0);
  stage4_g2(gA, l1, t, 1);
  bar_keep4();

  short *bA = l0, *bB = l1, *bC = l2;
  const int NK = NF / 64;
  for (int kk = 0; kk < NK; ++kk) {
    shortx8 bf[8];
    loadB(gB, kk * 64, NF, bf);
    __builtin_amdgcn_sched_barrier(0);
    if (kk + 2 < NK) stage4_g2(gA, bC, t, kk + 2);
    __builtin_amdgcn_sched_barrier(0);
    compute64w(bA, bf, acc, arow, lx, q);
    bar_keep4();
    short* tmp = bA; bA = bB; bB = bC; bC = tmp;
  }

  // epilogue: two 64-row chunks: bias -> bf16 -> LDS restage -> coalesced stores
  short* ep = (short*)smem;
  const int colL = wn * 64 + (lane & 15);
  const int rowL = (lane >> 4) << 2;
#pragma unroll
  for (int ch = 0; ch < 2; ch++) {
    if (wm == ch) {
#pragma unroll
      for (int j = 0; j < 4; j++) {
        float bv = b2[e * DIM + d0 + colL + j * 16];
#pragma unroll
        for (int i = 0; i < 4; i++) {
#pragma unroll
          for (int r = 0; r < 4; r++) {
            float o = acc[i][j][r] + bv;
            ep[(i * 16 + rowL + r) * 136 + colL + j * 16] = f2bf(o);
          }
        }
      }
    }
    __syncthreads();
    const int chunk = t & 15;
#pragma unroll
    for (int it = 0; it < 4; it++) {
      int r = (t >> 4) + 16 * it;
      shortx8 v = *(const shortx8*)&ep[r * 136 + chunk * 8];
      *(shortx8*)&oute[((size_t)e * CCAP + c0 + ch * 64 + r) * DIM + d0 + chunk * 8] = v;
    }
    __syncthreads();
  }
}

// ============ combine: out[token] = sum over selected (e,pos) of val * oute row ============
// also writes zeros for unselected tokens (out is not pre-zeroed)
__global__ __launch_bounds__(256) void k_combine(
    const short* __restrict__ oute, const int* __restrict__ cnt,
    const int* __restrict__ slots, const float* __restrict__ sel_val,
    float* __restrict__ out) {
  const int lane = threadIdx.x & 63;
  const int wid = threadIdx.x >> 6;
  const int n = blockIdx.x * 4 + wid;
  const int c = cnt[n];
  float acc[8];
#pragma unroll
  for (int k = 0; k < 8; k++) acc[k] = 0.f;
  for (int s = 0; s < c; ++s) {
    int sl = slots[n * 8 + s];
    int e = sl >> 16, pos = sl & 0xFFFF;
    float val = sel_val[e * CCAP + pos];
    shortx8 v = *(const shortx8*)&oute[((size_t)e * CCAP + pos) * DIM + lane * 8];
#pragma unroll
    for (int k = 0; k < 8; k++) acc[k] += val * bf2f(v[k]);
  }
  floatx4 o0 = {acc[0], acc[1], acc[2], acc[3]};
  floatx4 o1 = {acc[4], acc[5], acc[6], acc[7]};
  *(floatx4*)&out[(size_t)n * DIM + lane * 8] = o0;
  *(floatx4*)&out[(size_t)n * DIM + lane * 8 + 4] = o1;
}

extern "C" void kernel_launch(void* const* d_in, const int* in_sizes, int n_in,
                              void* d_out, int out_size, void* d_ws, size_t ws_size,
                              hipStream_t stream) {
  const float* x = (const float*)d_in[0];
  const float* Wr = (const float*)d_in[1];
  const float* W1 = (const float*)d_in[2];
  const float* b1 = (const float*)d_in[3];
  const float* W2 = (const float*)d_in[4];
  const float* b2 = (const float*)d_in[5];
  float* out = (float*)d_out;

  char* p = (char*)d_ws;
  size_t off = 0;
  auto carve = [&](size_t bytes) {
    void* r = p + off;
    off = (off + bytes + 255) & ~(size_t)255;
    return r;
  };
  short* xb = (short*)carve((size_t)N_TOK * DIM * 2);
  short* w1t = (short*)carve((size_t)NE * NF * DIM * 2);
  short* w2t = (short*)carve((size_t)NE * DIM * NF * 2);
  float* logitsT = (float*)carve((size_t)NE * N_TOK * 4);
  int* selidx = (int*)carve((size_t)NE * CCAP * 4);
  float* selval = (float*)carve((size_t)NE * CCAP * 4);
  int* cnt = (int*)carve((size_t)N_TOK * 4);
  int* slots = (int*)carve((size_t)N_TOK * 8 * 4);
  short* oute = (short*)carve((size_t)NE * CCAP * DIM * 2);
  const size_t hbytes = (size_t)CCAP * NF * 2;
  int g = 1;
  if (off + 8 * hbytes <= ws_size) g = 8;
  else if (off + 4 * hbytes <= ws_size) g = 4;
  else if (off + 2 * hbytes <= ws_size) g = 2;
  short* Hbuf = (short*)carve((size_t)g * hbytes);

  k_prep<<<5633, 256, 0, stream>>>(x, W1, W2, Wr, xb, w1t, w2t, logitsT, cnt);
  k_select<<<NE, 1024, 0, stream>>>(logitsT, selidx, selval, cnt, slots);
  for (int e0 = 0; e0 < NE; e0 += g) {
    k_gemm1<<<dim3(NF / 128, CCAP / 128, g), 256, 0, stream>>>(xb, w1t, b1, selidx, Hbuf, e0);
    k_gemm2<<<dim3(DIM / 128, CCAP / 128, g), 256, 0, stream>>>(Hbuf, w2t, b2, oute, e0);
  }
  k_combine<<<N_TOK / 4, 256, 0, stream>>>(oute, cnt, slots, selval, out);
}

// Round 7
// 477.642 us; speedup vs baseline: 1.2885x; 1.2493x over previous
//
#include <hip/hip_runtime.h>
#include <math.h>

#define N_TOK 32768
#define DIM 512
#define NE 8
#define NF 2048
#define CCAP 4096

typedef __attribute__((ext_vector_type(4))) float floatx4;
typedef __attribute__((ext_vector_type(8))) short shortx8;
typedef __attribute__((ext_vector_type(4))) short shortx4;

__device__ __forceinline__ short f2bf(float f) {
  union { float f; unsigned u; } v; v.f = f;
  unsigned r = v.u + 0x7FFFu + ((v.u >> 16) & 1u);
  return (short)(r >> 16);
}

__device__ __forceinline__ float bf2f(short s) {
  union { unsigned u; float f; } v; v.u = ((unsigned)(unsigned short)s) << 16;
  return v.f;
}

__device__ __forceinline__ unsigned f2key(float f) {
  union { float f; unsigned u; } v; v.f = f;
  return (v.u & 0x80000000u) ? ~v.u : (v.u | 0x80000000u);
}

__device__ __forceinline__ void gll16(const void* g, void* l) {
  __builtin_amdgcn_global_load_lds(
      (const __attribute__((address_space(1))) void*)g,
      (__attribute__((address_space(3))) void*)l, 16, 0, 0);
}

__device__ __forceinline__ float fast_gelu(float h) {
  float u = 0.7978845608f * (h + 0.044715f * h * h * h);
  float au = fabsf(u) * 2.885390082f;  // 2*log2(e)*|u|
  float z = __builtin_amdgcn_exp2f(au);
  float th = 1.0f - 2.0f * __builtin_amdgcn_rcpf(1.0f + z);
  th = copysignf(th, u);
  return 0.5f * h * (1.0f + th);
}

#define SB __builtin_amdgcn_sched_barrier(0)

// load 4 B-fragments (one g-group of a 64-K-step) into registers
__device__ __forceinline__ void loadBg(const short* gB, int kk, int g, int ldb, shortx8* bf) {
#pragma unroll
  for (int j = 0; j < 4; j++)
    bf[j] = *(const shortx8*)(gB + (size_t)j * 16 * ldb + kk * 64 + g * 32);
}

// half K-step of MFMA: one g-group, 8 i x 4 j (wave tile 128x64)
__device__ __forceinline__ void computeHalf(const short* ldsA, const shortx8* bf,
                                            floatx4 (*acc)[4], int arow, int lx, int q, int g) {
  const int pu = (((g << 2) | q) ^ lx) << 3;
#pragma unroll
  for (int i = 0; i < 8; i++) {
    shortx8 af = *(const shortx8*)&ldsA[(arow + i * 16) * 64 + pu];
#pragma unroll
    for (int j = 0; j < 4; j++)
      acc[i][j] = __builtin_amdgcn_mfma_f32_16x16x32_bf16(af, bf[j], acc[i][j], 0, 0, 0);
  }
}

// generalized expert->XCD swizzle (bijective; z in {1,2,4,8})
__device__ __forceinline__ void xcd_map(int& bx, int& by, int& zi) {
  int lid = blockIdx.x + gridDim.x * (blockIdx.y + gridDim.y * blockIdx.z);
  int k = 8 / (int)gridDim.z;
  int x = lid & 7, rem = lid >> 3;
  zi = x / k;
  int bxy = rem * k + (x % k);
  bx = bxy % (int)gridDim.x;
  by = bxy / (int)gridDim.x;
}

// ============ prep: W1/W2 transpose+convert, router logits (+x->bf16 fused), cnt zero ============
__global__ __launch_bounds__(256) void k_prep(
    const float* __restrict__ x, const float* __restrict__ W1,
    const float* __restrict__ W2, const float* __restrict__ Wr,
    short* __restrict__ xb, short* __restrict__ w1t, short* __restrict__ w2t,
    float* __restrict__ logitsT, int* __restrict__ cnt) {
  __shared__ float tl[64 * 68];
  const int b = blockIdx.x, t = threadIdx.x;
  if (b < 4096) {
    const float* in;
    short* o;
    int R, C, c0, r0;
    if (b < 2048) {
      int e = b >> 8, tlid = b & 255;
      in = W1 + (size_t)e * DIM * NF;
      o = w1t + (size_t)e * NF * DIM;
      R = DIM; C = NF;
      c0 = (tlid & 31) * 64; r0 = (tlid >> 5) * 64;
    } else {
      int bb = b - 2048;
      int e = bb >> 8, tlid = bb & 255;
      in = W2 + (size_t)e * NF * DIM;
      o = w2t + (size_t)e * DIM * NF;
      R = NF; C = DIM;
      c0 = (tlid & 7) * 64; r0 = (tlid >> 3) * 64;
    }
    const int r = t >> 4, cq = (t & 15) * 4;
#pragma unroll
    for (int ii = 0; ii < 4; ii++) {
      floatx4 v = *(const floatx4*)&in[(size_t)(r0 + r + 16 * ii) * C + c0 + cq];
      *(floatx4*)&tl[(r + 16 * ii) * 68 + cq] = v;
    }
    __syncthreads();
    const int cc = t >> 2, rq = (t & 3) * 16;
    shortx8 o0, o1;
#pragma unroll
    for (int k = 0; k < 8; k++) o0[k] = f2bf(tl[(rq + k) * 68 + cc]);
#pragma unroll
    for (int k = 0; k < 8; k++) o1[k] = f2bf(tl[(rq + 8 + k) * 68 + cc]);
    size_t ob = (size_t)(c0 + cc) * R + r0 + rq;
    *(shortx8*)&o[ob] = o0;
    *(shortx8*)&o[ob + 8] = o1;
  } else if (b < 5120) {
    // router logits (fp64 accumulate) + fused x->bf16 conversion
    const int lane = t & 63;
    const int wave = (b - 4096) * 4 + (t >> 6);
    float wr[64];
#pragma unroll
    for (int i = 0; i < 16; i++)
      *(floatx4*)&wr[i * 4] = *(const floatx4*)&Wr[lane * 64 + i * 4];
    for (int n = wave; n < N_TOK; n += 4096) {
      const float* xr = x + (size_t)n * DIM + lane * 8;
      floatx4 x0 = *(const floatx4*)xr;
      floatx4 x1 = *(const floatx4*)(xr + 4);
      float xs[8] = {x0.x, x0.y, x0.z, x0.w, x1.x, x1.y, x1.z, x1.w};
      // write xb (same rounding as before; each row covered exactly once)
      shortx8 sv;
#pragma unroll
      for (int j = 0; j < 8; j++) sv[j] = f2bf(xs[j]);
      *(shortx8*)&xb[(size_t)n * DIM + lane * 8] = sv;
      double acc[8];
#pragma unroll
      for (int e2 = 0; e2 < 8; e2++) acc[e2] = 0.0;
#pragma unroll
      for (int j = 0; j < 8; j++) {
        double xv = (double)xs[j];
#pragma unroll
        for (int e2 = 0; e2 < 8; e2++) acc[e2] += xv * (double)wr[j * 8 + e2];
      }
#pragma unroll
      for (int e2 = 0; e2 < 8; e2++) {
#pragma unroll
        for (int off2 = 32; off2 > 0; off2 >>= 1)
          acc[e2] += __shfl_xor(acc[e2], off2);
      }
      double rv = acc[0];
#pragma unroll
      for (int e2 = 1; e2 < 8; e2++)
        if (lane == e2) rv = acc[e2];
      if (lane < 8) logitsT[(size_t)lane * N_TOK + n] = (float)rv;
    }
  } else {
    // zero inverse-index counters
#pragma unroll
    for (int i = 0; i < 128; i++) cnt[t + 256 * i] = 0;
  }
}

// ============ exact top-C via register bisection + ballot compaction (+ inverse index) ============
__global__ __launch_bounds__(1024) void k_select(const float* __restrict__ logitsT,
                                                 int* __restrict__ sel_idx,
                                                 float* __restrict__ sel_val,
                                                 int* __restrict__ cnt,
                                                 int* __restrict__ slots) {
  __shared__ float redf[16];
  __shared__ unsigned redu[16];
  __shared__ float s_max, s_inv;
  __shared__ unsigned s_tot;
  __shared__ unsigned s_cnt[2];
  const int e = blockIdx.x, t = threadIdx.x;
  const int wid = t >> 6, lane = t & 63;
  const float* lg = logitsT + (size_t)e * N_TOK;
  float lv[32];
  unsigned kv[32];
#pragma unroll
  for (int i = 0; i < 32; i++) lv[i] = lg[i * 1024 + t];
#pragma unroll
  for (int i = 0; i < 32; i++) kv[i] = f2key(lv[i]);
  float m = lv[0];
#pragma unroll
  for (int i = 1; i < 32; i++) m = fmaxf(m, lv[i]);
#pragma unroll
  for (int o = 32; o > 0; o >>= 1) m = fmaxf(m, __shfl_xor(m, o));
  if (lane == 0) redf[wid] = m;
  __syncthreads();
  if (t == 0) {
    float v = redf[0];
    for (int i = 1; i < 16; i++) v = fmaxf(v, redf[i]);
    s_max = v;
  }
  __syncthreads();
  m = s_max;
  float s = 0.f;
#pragma unroll
  for (int i = 0; i < 32; i++) s += expf(lv[i] - m);
#pragma unroll
  for (int o = 32; o > 0; o >>= 1) s += __shfl_xor(s, o);
  if (lane == 0) redf[wid] = s;
  __syncthreads();
  if (t == 0) {
    float v = 0.f;
    for (int i = 0; i < 16; i++) v += redf[i];
    s_inv = 1.0f / v;
  }
  unsigned T = 0;
  for (int bb = 31; bb >= 0; --bb) {
    unsigned cand = T | (1u << bb);
    unsigned c = 0;
#pragma unroll
    for (int i = 0; i < 32; i++) c += (kv[i] >= cand) ? 1u : 0u;
#pragma unroll
    for (int o = 32; o > 0; o >>= 1) c += __shfl_xor(c, o);
    if (lane == 0) redu[wid] = c;
    __syncthreads();
    if (t == 0) {
      unsigned v = 0;
      for (int i = 0; i < 16; i++) v += redu[i];
      s_tot = v;
    }
    __syncthreads();
    if (s_tot >= CCAP) T = cand;
  }
  {
    unsigned c = 0;
#pragma unroll
    for (int i = 0; i < 32; i++) c += (kv[i] > T) ? 1u : 0u;
#pragma unroll
    for (int o = 32; o > 0; o >>= 1) c += __shfl_xor(c, o);
    if (lane == 0) redu[wid] = c;
    __syncthreads();
    if (t == 0) {
      unsigned v = 0;
      for (int i = 0; i < 16; i++) v += redu[i];
      s_tot = v;
      s_cnt[0] = 0;
      s_cnt[1] = 0;
    }
    __syncthreads();
  }
  const unsigned rr = CCAP - s_tot;
  const float inv = s_inv;
  const unsigned long long lmask = (1ull << lane) - 1ull;
#pragma unroll
  for (int i = 0; i < 32; i++) {
    int n = i * 1024 + t;
    bool gt = kv[i] > T;
    bool eq = kv[i] == T;
    unsigned long long mg = __ballot(gt);
    unsigned long long mq = __ballot(eq);
    unsigned bg = 0, bq = 0;
    if (lane == 0) {
      if (mg) bg = atomicAdd(&s_cnt[0], (unsigned)__popcll(mg));
      if (mq) bq = atomicAdd(&s_cnt[1], (unsigned)__popcll(mq));
    }
    bg = __shfl(bg, 0);
    bq = __shfl(bq, 0);
    int pos = -1;
    if (gt) {
      pos = (int)(bg + (unsigned)__popcll(mg & lmask));
    } else if (eq) {
      unsigned qq = bq + (unsigned)__popcll(mq & lmask);
      if (qq < rr) pos = (int)(CCAP - rr + qq);
    }
    if (pos >= 0) {
      sel_idx[e * CCAP + pos] = n;
      sel_val[e * CCAP + pos] = expf(lv[i] - m) * inv;
      int s2 = atomicAdd(&cnt[n], 1);
      slots[n * 8 + s2] = (e << 16) | pos;
    }
  }
}

// ============ GEMM1: H = gelu(gather(xb)[256-tile,512] @ W1 + b1) ============
// Round-3 geometry (256x128 block, 4 waves of 128x64, 2x32KB A-dbuf) + half-step
// B register pipeline: B(g1) covered by g0 MFMAs, next-step B(g0) covered by g1
// MFMAs + barrier. Register-neutral vs round 3 (peak B-liveness still 32 VGPR).
__global__ __launch_bounds__(256, 2) void k_gemm1(
    const short* __restrict__ xb, const short* __restrict__ w1t,
    const float* __restrict__ b1, const int* __restrict__ sel_idx,
    short* __restrict__ H, int e0) {
  __shared__ char smem[256 * 136 * 2];  // 69632 B; A dbuf = 2x32768, epilogue reuses all
  short* l0 = (short*)smem;
  short* l1 = (short*)(smem + 32768);

  int bx, by, zi;
  xcd_map(bx, by, zi);
  const int e = e0 + zi;
  const int c0 = by * 256;
  const int f0 = bx * 128;
  const int t = threadIdx.x;
  const int lane = t & 63;
  const int w = t >> 6;
  const int wm = w & 1, wn = w >> 1;
  const int row8 = t >> 3;
  const int su = (t & 7) ^ (row8 & 7);

  unsigned offA[8];  // 32-bit element offsets into xb (saves 8 VGPR vs pointers)
#pragma unroll
  for (int i = 0; i < 8; i++) {
    int tok = sel_idx[e * CCAP + c0 + row8 + i * 32];
    offA[i] = (unsigned)tok * DIM + su * 8;
  }
  const short* gB = w1t + ((size_t)(e * NF + f0 + wn * 64 + (lane & 15))) * DIM + (lane >> 4) * 8;

  floatx4 acc[8][4];
#pragma unroll
  for (int i = 0; i < 8; i++)
#pragma unroll
    for (int j = 0; j < 4; j++) acc[i][j] = (floatx4){0.f, 0.f, 0.f, 0.f};

  const int arow = wm * 128 + (lane & 15);
  const int lx = lane & 7, q = lane >> 4;

  shortx8 bfE[4], bfO[4];
  // prologue: B(0,g0) + stage tile 0
  loadBg(gB, 0, 0, DIM, bfE);
  SB;
#pragma unroll
  for (int i = 0; i < 8; i++) gll16(xb + offA[i], l0 + i * 2048 + t * 8);
  __syncthreads();

  short *cur = l0, *nxt = l1;
  const int NK = DIM / 64;
  for (int kk = 0; kk < NK; ++kk) {
    loadBg(gB, kk, 1, DIM, bfO);  // B(kk,g1): covered by g0 compute
    SB;
    if (kk + 1 < NK) {            // A prefetch: covered by full step + drained at barrier
#pragma unroll
      for (int i = 0; i < 8; i++)
        gll16(xb + offA[i] + (kk + 1) * 64, nxt + i * 2048 + t * 8);
    }
    SB;
    computeHalf(cur, bfE, acc, arow, lx, q, 0);
    SB;
    if (kk + 1 < NK) loadBg(gB, kk + 1, 0, DIM, bfE);  // B(kk+1,g0): covered by g1+barrier
    SB;
    computeHalf(cur, bfO, acc, arow, lx, q, 1);
    __syncthreads();
    short* tmp = cur; cur = nxt; nxt = tmp;
  }

  // epilogue: bias+gelu -> LDS restage (stride 136) -> coalesced stores
  short* ep = (short*)smem;
  const int colL = wn * 64 + (lane & 15);
  const int rowL = wm * 128 + ((lane >> 4) << 2);
#pragma unroll
  for (int j = 0; j < 4; j++) {
    float bv = b1[e * NF + f0 + colL + j * 16];
#pragma unroll
    for (int i = 0; i < 8; i++) {
#pragma unroll
      for (int r = 0; r < 4; r++) {
        float h = acc[i][j][r] + bv;
        ep[(rowL + i * 16 + r) * 136 + colL + j * 16] = f2bf(fast_gelu(h));
      }
    }
  }
  __syncthreads();
  short* Hp = H + (size_t)zi * CCAP * NF;
  const int chunk = t & 15;
#pragma unroll
  for (int it = 0; it < 16; it++) {
    int r = (t >> 4) + 16 * it;
    shortx8 v = *(const shortx8*)&ep[r * 136 + chunk * 8];
    *(shortx8*)&Hp[(size_t)(c0 + r) * NF + f0 + chunk * 8] = v;
  }
}

// ============ GEMM2: oute[e] = H @ W2 + b2 (unscaled, bf16, NO atomics) ============
// Same structure; K=2048 -> 32 steps.
__global__ __launch_bounds__(256, 2) void k_gemm2(
    const short* __restrict__ H, const short* __restrict__ w2t,
    const float* __restrict__ b2, short* __restrict__ oute, int e0) {
  __shared__ char smem[256 * 136 * 2];
  short* l0 = (short*)smem;
  short* l1 = (short*)(smem + 32768);

  int bx, by, zi;
  xcd_map(bx, by, zi);
  const int e = e0 + zi;
  const int c0 = by * 256;
  const int d0 = bx * 128;
  const int t = threadIdx.x;
  const int lane = t & 63;
  const int w = t >> 6;
  const int wm = w & 1, wn = w >> 1;
  const int row8 = t >> 3;
  const int su = (t & 7) ^ (row8 & 7);

  const short* gA = H + ((size_t)zi * CCAP + c0 + row8) * NF + su * 8;
  const short* gB = w2t + ((size_t)(e * DIM + d0 + wn * 64 + (lane & 15))) * NF + (lane >> 4) * 8;

  floatx4 acc[8][4];
#pragma unroll
  for (int i = 0; i < 8; i++)
#pragma unroll
    for (int j = 0; j < 4; j++) acc[i][j] = (floatx4){0.f, 0.f, 0.f, 0.f};

  const int arow = wm * 128 + (lane & 15);
  const int lx = lane & 7, q = lane >> 4;

  shortx8 bfE[4], bfO[4];
  loadBg(gB, 0, 0, NF, bfE);
  SB;
#pragma unroll
  for (int i = 0; i < 8; i++)
    gll16(gA + (size_t)i * 32 * NF, l0 + i * 2048 + t * 8);
  __syncthreads();

  short *cur = l0, *nxt = l1;
  const int NK = NF / 64;
  for (int kk = 0; kk < NK; ++kk) {
    loadBg(gB, kk, 1, NF, bfO);
    SB;
    if (kk + 1 < NK) {
#pragma unroll
      for (int i = 0; i < 8; i++)
        gll16(gA + (size_t)i * 32 * NF + (kk + 1) * 64, nxt + i * 2048 + t * 8);
    }
    SB;
    computeHalf(cur, bfE, acc, arow, lx, q, 0);
    SB;
    if (kk + 1 < NK) loadBg(gB, kk + 1, 0, NF, bfE);
    SB;
    computeHalf(cur, bfO, acc, arow, lx, q, 1);
    __syncthreads();
    short* tmp = cur; cur = nxt; nxt = tmp;
  }

  // epilogue: bias -> bf16 -> LDS restage -> coalesced 256B-row stores
  short* ep = (short*)smem;
  const int colL = wn * 64 + (lane & 15);
  const int rowL = wm * 128 + ((lane >> 4) << 2);
#pragma unroll
  for (int j = 0; j < 4; j++) {
    float bv = b2[e * DIM + d0 + colL + j * 16];
#pragma unroll
    for (int i = 0; i < 8; i++) {
#pragma unroll
      for (int r = 0; r < 4; r++) {
        float o = acc[i][j][r] + bv;
        ep[(rowL + i * 16 + r) * 136 + colL + j * 16] = f2bf(o);
      }
    }
  }
  __syncthreads();
  const int chunk = t & 15;
#pragma unroll
  for (int it = 0; it < 16; it++) {
    int r = (t >> 4) + 16 * it;
    shortx8 v = *(const shortx8*)&ep[r * 136 + chunk * 8];
    *(shortx8*)&oute[((size_t)e * CCAP + c0 + r) * DIM + d0 + chunk * 8] = v;
  }
}

// ============ combine: out[token] = sum over selected (e,pos) of val * oute row ============
// also writes zeros for unselected tokens (out is not pre-zeroed)
__global__ __launch_bounds__(256) void k_combine(
    const short* __restrict__ oute, const int* __restrict__ cnt,
    const int* __restrict__ slots, const float* __restrict__ sel_val,
    float* __restrict__ out) {
  const int lane = threadIdx.x & 63;
  const int wid = threadIdx.x >> 6;
  const int n = blockIdx.x * 4 + wid;
  const int c = cnt[n];
  float acc[8];
#pragma unroll
  for (int k = 0; k < 8; k++) acc[k] = 0.f;
  for (int s = 0; s < c; ++s) {
    int sl = slots[n * 8 + s];
    int e = sl >> 16, pos = sl & 0xFFFF;
    float val = sel_val[e * CCAP + pos];
    shortx8 v = *(const shortx8*)&oute[((size_t)e * CCAP + pos) * DIM + lane * 8];
#pragma unroll
    for (int k = 0; k < 8; k++) acc[k] += val * bf2f(v[k]);
  }
  floatx4 o0 = {acc[0], acc[1], acc[2], acc[3]};
  floatx4 o1 = {acc[4], acc[5], acc[6], acc[7]};
  *(floatx4*)&out[(size_t)n * DIM + lane * 8] = o0;
  *(floatx4*)&out[(size_t)n * DIM + lane * 8 + 4] = o1;
}

extern "C" void kernel_launch(void* const* d_in, const int* in_sizes, int n_in,
                              void* d_out, int out_size, void* d_ws, size_t ws_size,
                              hipStream_t stream) {
  const float* x = (const float*)d_in[0];
  const float* Wr = (const float*)d_in[1];
  const float* W1 = (const float*)d_in[2];
  const float* b1 = (const float*)d_in[3];
  const float* W2 = (const float*)d_in[4];
  const float* b2 = (const float*)d_in[5];
  float* out = (float*)d_out;

  char* p = (char*)d_ws;
  size_t off = 0;
  auto carve = [&](size_t bytes) {
    void* r = p + off;
    off = (off + bytes + 255) & ~(size_t)255;
    return r;
  };
  short* xb = (short*)carve((size_t)N_TOK * DIM * 2);
  short* w1t = (short*)carve((size_t)NE * NF * DIM * 2);
  short* w2t = (short*)carve((size_t)NE * DIM * NF * 2);
  float* logitsT = (float*)carve((size_t)NE * N_TOK * 4);
  int* selidx = (int*)carve((size_t)NE * CCAP * 4);
  float* selval = (float*)carve((size_t)NE * CCAP * 4);
  int* cnt = (int*)carve((size_t)N_TOK * 4);
  int* slots = (int*)carve((size_t)N_TOK * 8 * 4);
  short* oute = (short*)carve((size_t)NE * CCAP * DIM * 2);
  const size_t hbytes = (size_t)CCAP * NF * 2;
  int g = 1;
  if (off + 8 * hbytes <= ws_size) g = 8;
  else if (off + 4 * hbytes <= ws_size) g = 4;
  else if (off + 2 * hbytes <= ws_size) g = 2;
  short* Hbuf = (short*)carve((size_t)g * hbytes);

  k_prep<<<5121, 256, 0, stream>>>(x, W1, W2, Wr, xb, w1t, w2t, logitsT, cnt);
  k_select<<<NE, 1024, 0, stream>>>(logitsT, selidx, selval, cnt, slots);
  for (int e0 = 0; e0 < NE; e0 += g) {
    k_gemm1<<<dim3(NF / 128, CCAP / 256, g), 256, 0, stream>>>(xb, w1t, b1, selidx, Hbuf, e0);
    k_gemm2<<<dim3(DIM / 128, CCAP / 256, g), 256, 0, stream>>>(Hbuf, w2t, b2, oute, e0);
  }
  k_combine<<<N_TOK / 4, 256, 0, stream>>>(oute, cnt, slots, selval, out);
}